// Round 10
// baseline (2551.613 us; speedup 1.0000x reference)
//
#include <hip/hip_runtime.h>
#include <math.h>

#define BATCH 16384
#define HDIM  512
#define VOCAB 32
#define STEPS 20
#define G4    2048

typedef _Float16 f16;
typedef _Float16 f16x8 __attribute__((ext_vector_type(8)));
typedef float    f32x16 __attribute__((ext_vector_type(16)));

#define SH   256.0f            // h pre-scale before fp16 split
#define SW   1024.0f           // W pre-scale before fp16 split
#define SINV (1.0f / (SH * SW))

// Fragment-ordered global images (granule = 16 B = 8 f16 = one lane's A/B frag):
//  hT  [kk:32][mb:512][lane:64]          granule(kk,mb,lane) =
//        h[m = mb*32 + (lane&31)][k = kk*16 + (lane>>5)*8 .. +8]
//  Wimg row r = jb*128 + kc*8 + ks*4 + g, granule(r,lane) =
//        W[n = g*512 + jb*32 + (lane&31)][k = kc*32 + ks*16 + (lane>>5)*8 .. +8]
//  Wout row r = kc*2 + ks (32 rows), granule(r,lane) =
//        W_out[v = lane&31][k = kc*32 + ks*16 + (lane>>5)*8 .. +8]

__device__ __forceinline__ void gload16(const void* g, void* l) {
#if defined(__has_builtin) && __has_builtin(__builtin_amdgcn_global_load_lds)
    __builtin_amdgcn_global_load_lds(
        (const __attribute__((address_space(1))) void*)g,
        (__attribute__((address_space(3))) void*)l, 16, 0, 0);
#else
    *(float4*)l = *(const float4*)g;
#endif
}

__device__ __forceinline__ float fsig(float x)  { return 1.0f / (1.0f + __expf(-x)); }
__device__ __forceinline__ float ftanh(float x) { return 1.0f - 2.0f / (__expf(2.0f * x) + 1.0f); }

// ---------------------------------------------------------------------------
// init / prep kernels (once per launch, outside the step loop)
// ---------------------------------------------------------------------------
__global__ void init_xb_kernel(const float* __restrict__ W_ih,
                               const float* __restrict__ b_ih,
                               const float* __restrict__ b_hh,
                               const float* __restrict__ x0,
                               float* __restrict__ xb) {
    int n = blockIdx.x * blockDim.x + threadIdx.x;
    if (n >= G4) return;
    float s = b_ih[n] + b_hh[n];
    const float* wr = W_ih + (size_t)n * VOCAB;
    #pragma unroll
    for (int v = 0; v < VOCAB; v++) s += wr[v] * x0[v];
    xb[n] = s;
}

__global__ void init_mask_kernel(float* __restrict__ mask) {
    int b = blockIdx.x * blockDim.x + threadIdx.x;
    if (b < BATCH) mask[b] = 1.0f;
}

// W_hh (fp32 [2048][512]) -> fragment-ordered split images (131072 granules)
__global__ void wimg_kernel(const float* __restrict__ W_hh,
                            f16* __restrict__ Wh, f16* __restrict__ Wl) {
    size_t g  = (size_t)blockIdx.x * 256 + threadIdx.x;   // granule id
    int ln = g & 63;  size_t r = g >> 6;                   // r = ((jb*16+kc)*2+ks)*4+gg
    int gg = r & 3;   size_t r2 = r >> 2;
    int ks = r2 & 1;  size_t r3 = r2 >> 1;
    int kc = r3 & 15; int jb = (int)(r3 >> 4);
    int n = gg * 512 + jb * 32 + (ln & 31);
    int k = kc * 32 + ks * 16 + (ln >> 5) * 8;
    const float* s = W_hh + (size_t)n * HDIM + k;
    f16x8 vh, vl;
    #pragma unroll
    for (int i = 0; i < 8; i++) {
        float x = s[i] * SW;
        f16 h = (f16)x;
        vh[i] = h;
        vl[i] = (f16)(x - (float)h);
    }
    *(f16x8*)(Wh + g * 8) = vh;
    *(f16x8*)(Wl + g * 8) = vl;
}

// W_out (fp32 [32][512]) -> fragment-ordered split images (2048 granules)
__global__ void woutimg_kernel(const float* __restrict__ W_out,
                               f16* __restrict__ Oh, f16* __restrict__ Ol) {
    int g  = blockIdx.x * 256 + threadIdx.x;   // 0..2047
    int ln = g & 63;
    int r  = g >> 6;                            // 0..31 = kc*2 + ks
    int kc = r >> 1, ks = r & 1;
    int v  = ln & 31;
    int k  = kc * 32 + ks * 16 + (ln >> 5) * 8;
    const float* s = W_out + (size_t)v * HDIM + k;
    f16x8 vh, vl;
    #pragma unroll
    for (int i = 0; i < 8; i++) {
        float x = s[i] * SW;
        f16 h = (f16)x;
        vh[i] = h;
        vl[i] = (f16)(x - (float)h);
    }
    *(f16x8*)(Oh + (size_t)g * 8) = vh;
    *(f16x8*)(Ol + (size_t)g * 8) = vl;
}

// enc_h (fp32 [16384][512]) -> fragment-ordered split hT images (1048576 granules)
__global__ void hT_init_kernel(const float* __restrict__ src,
                               f16* __restrict__ dh, f16* __restrict__ dl) {
    size_t g = (size_t)blockIdx.x * 256 + threadIdx.x;    // granule id
    int ln = g & 63;  size_t r = g >> 6;                   // r = kk*512 + mb
    int mb = (int)(r & 511); int kk = (int)(r >> 9);
    int m = mb * 32 + (ln & 31);
    int k = kk * 16 + (ln >> 5) * 8;
    const float* s = src + (size_t)m * HDIM + k;
    f16x8 vh, vl;
    #pragma unroll
    for (int i = 0; i < 8; i++) {
        float x = s[i] * SH;
        f16 h = (f16)x;
        vh[i] = h;
        vl[i] = (f16)(x - (float)h);
    }
    *(f16x8*)(dh + g * 8) = vh;
    *(f16x8*)(dl + g * 8) = vl;
}

// ---------------------------------------------------------------------------
// Output-step body: one wave computes logits/argmax/softmax for 32 batch rows.
// No LDS, no barriers.
// ---------------------------------------------------------------------------
__device__ __forceinline__ void out_body(int lane, int mb,
        const f16* __restrict__ hTh, const f16* __restrict__ hTl,
        const f16* __restrict__ Oh,  const f16* __restrict__ Ol,
        const float* __restrict__ b_out,
        float* __restrict__ mask, float* __restrict__ msg_t,
        float* __restrict__ maskout_t, float* __restrict__ lp_part, int eos) {
    const int half = lane >> 5;
    const int l31  = lane & 31;

    f32x16 acc;
    #pragma unroll
    for (int r = 0; r < 16; r++) acc[r] = 0.0f;

    f16x8 ah[3][2], al[3][2], bh[3][2], bl[3][2];
    auto load_frags = [&](int kc, int buf) {
        #pragma unroll
        for (int ks = 0; ks < 2; ks++) {
            size_t ga = ((size_t)(kc * 2 + ks) * 512 + mb) * 64 + lane;
            size_t gb = ((size_t)(kc * 2 + ks)) * 64 + lane;
            ah[buf][ks] = *(const f16x8*)(hTh + ga * 8);
            al[buf][ks] = *(const f16x8*)(hTl + ga * 8);
            bh[buf][ks] = *(const f16x8*)(Oh + gb * 8);
            bl[buf][ks] = *(const f16x8*)(Ol + gb * 8);
        }
    };

    load_frags(0, 0);
    load_frags(1, 1);
    for (int kc = 0; kc < 16; kc++) {
        if (kc < 14) load_frags(kc + 2, (kc + 2) % 3);
        int b = kc % 3;
        #pragma unroll
        for (int ks = 0; ks < 2; ks++) {
            acc = __builtin_amdgcn_mfma_f32_32x32x16_f16(ah[b][ks], bh[b][ks], acc, 0, 0, 0);
            acc = __builtin_amdgcn_mfma_f32_32x32x16_f16(ah[b][ks], bl[b][ks], acc, 0, 0, 0);
            acc = __builtin_amdgcn_mfma_f32_32x32x16_f16(al[b][ks], bh[b][ks], acc, 0, 0, 0);
        }
    }

    const float bo = b_out[l31];
    const int   m0 = mb * 32;
    float lpacc = 0.0f;

    #pragma unroll
    for (int reg = 0; reg < 16; reg++) {
        int row = (reg & 3) + 8 * (reg >> 2) + 4 * half;
        int m   = m0 + row;
        float logit = acc[reg] * SINV + bo;

        float mval = logit;
        int   midx = l31;
        #pragma unroll
        for (int off = 16; off > 0; off >>= 1) {
            float ov = __shfl_xor(mval, off, 32);
            int   oi = __shfl_xor(midx, off, 32);
            if (ov > mval || (ov == mval && oi < midx)) { mval = ov; midx = oi; }
        }
        float s = __expf(logit - mval);
        #pragma unroll
        for (int off = 16; off > 0; off >>= 1) s += __shfl_xor(s, off, 32);

        msg_t[(size_t)m * VOCAB + l31] = (l31 == midx) ? 1.0f : 0.0f;
        if (l31 == 0) {
            float mo = mask[m];
            maskout_t[m] = mo;
            lpacc += mo * (-__logf(s));
            if (midx == eos) mask[m] = 0.0f;
        }
    }
    lpacc += __shfl_xor(lpacc, 32);   // fold lane 32's partial into lane 0
    if (lane == 0) lp_part[mb] = lpacc;
}

// ---------------------------------------------------------------------------
// Fused step kernel.  Blocks 0..127 (4 waves each): output step for h(t-1),
// placed FIRST so gemm blocks backfill behind them.  Blocks 128..2175: MFMA
// GEMM (3-pass fp16 split) + LSTM cell -> h(t) images.
// Block tile 128m x 128n; wave tile 32m x 128n (acc = 64 AGPR); 64 arch VGPR
// + 64 acc = 128 total -> 4 waves/SIMD via __launch_bounds__(256, 4).
// Swizzle gb = jb*128 + mt: since 128 % 8 == 0, all 16 blocks sharing an
// A-slice (same mt) land on the same XCD (XCD = mt%8) -> per-XCD A working
// set = 16 slices = 4 MB = L2 size; A fetched ~once per XCD.
// mfma_f32_32x32x16_f16: D[row=(reg&3)+8*(reg>>2)+4*(lane>>5)][col=lane&31].
// ---------------------------------------------------------------------------
__global__ __launch_bounds__(256, 4)
void step_fused(const f16* __restrict__ hT_h, const f16* __restrict__ hT_l,
                f16* __restrict__ hTo_h, f16* __restrict__ hTo_l,
                float* __restrict__ c,
                const f16* __restrict__ Wimg_h, const f16* __restrict__ Wimg_l,
                const float* __restrict__ xb,
                const f16* __restrict__ Oh, const f16* __restrict__ Ol,
                const float* __restrict__ b_out,
                float* __restrict__ mask,
                float* __restrict__ msg_p,      // step t-1 outputs
                float* __restrict__ maskout_p,
                float* __restrict__ lp_p,
                const int* __restrict__ eos_ptr,
                int has_out) {
    __shared__ __align__(16) char smem_raw[34048];   // 32 KB B dbuf | 16.9 KB hstage
    f16* Blds = (f16*)smem_raw;   // row = (buf*16 + sp*8 + ks*4 + g), 512 f16/row

    const int tid  = threadIdx.x;
    const int lane = tid & 63;
    const int wave = tid >> 6;
    const int bid  = blockIdx.x;

    if (bid < 128) {                // ---- output-step role (for h(t-1)) ----
        if (!has_out) return;
        int mb = bid * 4 + wave;                   // 0..511
        out_body(lane, mb, hT_h, hT_l, Oh, Ol, b_out,
                 mask, msg_p, maskout_p, lp_p, *eos_ptr);
        return;
    }

    // ---- GEMM role ----
    const int gb   = bid - 128;       // 0..2047
    const int jb   = gb >> 7;         // n-slice (slow)
    const int mt   = gb & 127;        // 128-m tile (fast; XCD = mt%8 pinned)
    const int spw  = wave >> 1;       // staging: split image
    const int ksw  = wave & 1;        // staging: k-sub
    const int mbA  = mt * 4 + wave;   // this wave's 32-m granule row
    const int m0   = mt * 128;
    const int j0   = jb * 32;
    const int half = lane >> 5;
    const int l31  = lane & 31;

    f32x16 acc[4];                    // [gate] for this wave's 32m x 32j
    #pragma unroll
    for (int g = 0; g < 4; g++)
        #pragma unroll
        for (int r = 0; r < 16; r++) acc[g][r] = 0.0f;

    const f16* bsrc0 = (spw ? Wimg_l : Wimg_h)
                     + ((size_t)jb * 128 + ksw * 4) * 512 + lane * 8;
    f16* bdst0 = Blds + (size_t)(spw * 8 + ksw * 4) * 512 + lane * 8;

    auto stage_b = [&](int kc, int buf) {
        const f16* s = bsrc0 + (size_t)kc * 4096;
        f16* d = bdst0 + buf * 16 * 512;
        #pragma unroll
        for (int g = 0; g < 4; g++)
            gload16(s + g * 512, d + g * 512);
    };

    const size_t abase0 = (size_t)mbA * 512 + lane * 8;
    auto load_ah = [&](int kc, f16x8 (&dst)[2]) {
        #pragma unroll
        for (int ks = 0; ks < 2; ks++)
            dst[ks] = *(const f16x8*)(hT_h + abase0
                           + (size_t)(kc * 2 + ks) * (512 * 512));
    };
    auto load_al = [&](int kc, f16x8 (&dst)[2]) {
        #pragma unroll
        for (int ks = 0; ks < 2; ks++)
            dst[ks] = *(const f16x8*)(hT_l + abase0
                           + (size_t)(kc * 2 + ks) * (512 * 512));
    };

    // pass-major order; per-accumulator accumulation order (hh, hl, lh) is
    // unchanged from prior rounds -> bit-identical results.
    auto compute = [&](f16x8 (&ah)[2], f16x8 (&al)[2], int buf) {
        #pragma unroll
        for (int ks = 0; ks < 2; ks++) {
            f16x8 bh[4], bl[4];
            #pragma unroll
            for (int g = 0; g < 4; g++) {
                bh[g] = *(const f16x8*)(Blds + (size_t)(buf * 16 + ks * 4 + g) * 512 + lane * 8);
                bl[g] = *(const f16x8*)(Blds + (size_t)(buf * 16 + 8 + ks * 4 + g) * 512 + lane * 8);
            }
            #pragma unroll
            for (int g = 0; g < 4; g++)
                acc[g] = __builtin_amdgcn_mfma_f32_32x32x16_f16(ah[ks], bh[g], acc[g], 0, 0, 0);
            #pragma unroll
            for (int g = 0; g < 4; g++)
                acc[g] = __builtin_amdgcn_mfma_f32_32x32x16_f16(ah[ks], bl[g], acc[g], 0, 0, 0);
            #pragma unroll
            for (int g = 0; g < 4; g++)
                acc[g] = __builtin_amdgcn_mfma_f32_32x32x16_f16(al[ks], bh[g], acc[g], 0, 0, 0);
        }
    };

    f16x8 ah0[2], ah1[2], al0[2], al1[2];
    stage_b(0, 0);
    load_ah(0, ah0);
    load_al(0, al0);
    for (int kc2 = 0; kc2 < 8; kc2++) {
        const int kc = kc2 * 2;
        __syncthreads();                 // buf0(kc) + ah0/al0 ready (issued 1 chunk ago)
        stage_b(kc + 1, 1);
        load_ah(kc + 1, ah1);
        load_al(kc + 1, al1);
        compute(ah0, al0, 0);
        __syncthreads();                 // buf1(kc+1) + ah1/al1 ready
        stage_b(kc + 2, 0);              // kc+2==16 on last iter: benign overrun
        load_ah(kc + 2, ah0);            //   (reads stay inside workspace)
        load_al(kc + 2, al0);
        compute(ah1, al1, 1);
    }

    // ---- epilogue: cell update + hT-image production via LDS bounce ----
    __syncthreads();
    unsigned int* hstage = (unsigned int*)smem_raw;   // [m:128][j:33] packed (hi,lo)

    const float xbi = xb[0 * HDIM + j0 + l31];
    const float xbf = xb[1 * HDIM + j0 + l31];
    const float xbg = xb[2 * HDIM + j0 + l31];
    const float xbo = xb[3 * HDIM + j0 + l31];
    #pragma unroll
    for (int reg = 0; reg < 16; reg++) {
        int row = (reg & 3) + 8 * (reg >> 2) + 4 * half;
        int ml  = wave * 32 + row;                 // local m (0..127)
        float gi = acc[0][reg] * SINV + xbi;
        float gf = acc[1][reg] * SINV + xbf;
        float gg = acc[2][reg] * SINV + xbg;
        float go = acc[3][reg] * SINV + xbo;
        float si = fsig(gi);
        float sf = fsig(gf);
        float tg = ftanh(gg);
        float so = fsig(go);
        size_t idx = (size_t)(m0 + ml) * HDIM + j0 + l31;
        float cn = sf * c[idx] + si * tg;
        c[idx] = cn;
        float hs = so * ftanh(cn) * SH;
        f16 hh = (f16)hs;
        f16 hl = (f16)(hs - (float)hh);
        union { f16 h[2]; unsigned int u; } pk;
        pk.h[0] = hh; pk.h[1] = hl;
        hstage[ml * 33 + l31] = pk.u;
    }
    __syncthreads();

    // emit 512 granules: q = (ksp<<8)|(mbl<<6)|ln
    #pragma unroll
    for (int s = 0; s < 2; s++) {
        int q   = tid + s * 256;
        int ksp = q >> 8;
        int mbl = (q >> 6) & 3;
        int ln  = q & 63;
        int mrow = mbl * 32 + (ln & 31);           // local m (0..127)
        int jj8  = ksp * 16 + (ln >> 5) * 8;
        f16x8 vh, vl;
        #pragma unroll
        for (int i = 0; i < 8; i++) {
            union { unsigned int u; f16 h[2]; } pk;
            pk.u = hstage[mrow * 33 + jj8 + i];
            vh[i] = pk.h[0];
            vl[i] = pk.h[1];
        }
        size_t gq = ((size_t)(jb * 2 + ksp) * 512 + mt * 4 + mbl) * 64 + ln;
        *(f16x8*)(hTo_h + gq * 8) = vh;
        *(f16x8*)(hTo_l + gq * 8) = vl;
    }
}

// standalone output step (final step only)
__global__ __launch_bounds__(64)
void out_mfma(const f16* __restrict__ hTh, const f16* __restrict__ hTl,
              const f16* __restrict__ Oh, const f16* __restrict__ Ol,
              const float* __restrict__ b_out,
              float* __restrict__ mask,
              float* __restrict__ msg_t,
              float* __restrict__ maskout_t,
              float* __restrict__ lp_part,
              const int* __restrict__ eos_ptr) {
    out_body(threadIdx.x, blockIdx.x, hTh, hTl, Oh, Ol, b_out,
             mask, msg_t, maskout_t, lp_part, *eos_ptr);
}

__global__ void reduce_lp_kernel(const float* __restrict__ parts, int n,
                                 float* __restrict__ out) {
    __shared__ float sm[256];
    float s = 0.0f;
    for (int i = threadIdx.x; i < n; i += 256) s += parts[i];
    sm[threadIdx.x] = s;
    __syncthreads();
    for (int off = 128; off > 0; off >>= 1) {
        if (threadIdx.x < off) sm[threadIdx.x] += sm[threadIdx.x + off];
        __syncthreads();
    }
    if (threadIdx.x == 0) *out = sm[0];
}

// ---------------------------------------------------------------------------
extern "C" void kernel_launch(void* const* d_in, const int* in_sizes, int n_in,
                              void* d_out, int out_size, void* d_ws, size_t ws_size,
                              hipStream_t stream) {
    const float* enc_h  = (const float*)d_in[0];
    const float* enc_c  = (const float*)d_in[1];
    const float* W_ih   = (const float*)d_in[2];
    const float* b_ih   = (const float*)d_in[3];
    const float* W_hh   = (const float*)d_in[4];
    const float* b_hh   = (const float*)d_in[5];
    const float* W_out  = (const float*)d_in[6];
    const float* b_out  = (const float*)d_in[7];
    const float* x0     = (const float*)d_in[8];
    const int*   eosP   = (const int*)d_in[9];

    float* out     = (float*)d_out;
    float* msg     = out;                                   // [20,16384,32]
    float* maskout = out + (size_t)STEPS * BATCH * VOCAB;   // [20,1,16384]
    float* lp_out  = maskout + (size_t)STEPS * BATCH;       // scalar

    const size_t NH = (size_t)BATCH * HDIM;                 // 8388608
    char* w = (char*)d_ws;
    f16* hTh_a = (f16*)w;            w += NH * sizeof(f16);
    f16* hTl_a = (f16*)w;            w += NH * sizeof(f16);
    f16* hTh_b = (f16*)w;            w += NH * sizeof(f16);
    f16* hTl_b = (f16*)w;            w += NH * sizeof(f16);
    float* cbuf = (float*)w;         w += NH * sizeof(float);
    f16* Wimg_h = (f16*)w;           w += (size_t)G4 * HDIM * sizeof(f16);
    f16* Wimg_l = (f16*)w;           w += (size_t)G4 * HDIM * sizeof(f16);
    f16* Wout_h = (f16*)w;           w += (size_t)VOCAB * HDIM * sizeof(f16);
    f16* Wout_l = (f16*)w;           w += (size_t)VOCAB * HDIM * sizeof(f16);
    float* xb = (float*)w;           w += G4 * sizeof(float);
    float* maskbuf = (float*)w;      w += BATCH * sizeof(float);
    float* lp_parts = (float*)w;     // STEPS * 512 floats

    hipMemcpyAsync(cbuf, enc_c, NH * sizeof(float), hipMemcpyDeviceToDevice, stream);
    init_mask_kernel<<<(BATCH + 255) / 256, 256, 0, stream>>>(maskbuf);
    init_xb_kernel<<<(G4 + 255) / 256, 256, 0, stream>>>(W_ih, b_ih, b_hh, x0, xb);
    wimg_kernel<<<(G4 * HDIM / 8) / 256, 256, 0, stream>>>(W_hh, Wimg_h, Wimg_l);
    woutimg_kernel<<<8, 256, 0, stream>>>(W_out, Wout_h, Wout_l);
    hT_init_kernel<<<(int)((NH / 8) / 256), 256, 0, stream>>>(enc_h, hTh_a, hTl_a);

    for (int t = 0; t < STEPS; t++) {
        const f16* hi_in = (t & 1) ? hTh_b : hTh_a;
        const f16* lo_in = (t & 1) ? hTl_b : hTl_a;
        f16* hi_out      = (t & 1) ? hTh_a : hTh_b;
        f16* lo_out      = (t & 1) ? hTl_a : hTl_b;
        int tp = (t > 0) ? (t - 1) : 0;   // previous step (outputs written iff t>0)
        step_fused<<<2176, 256, 0, stream>>>(
            hi_in, lo_in, hi_out, lo_out, cbuf, Wimg_h, Wimg_l, xb,
            Wout_h, Wout_l, b_out, maskbuf,
            msg + (size_t)tp * BATCH * VOCAB,
            maskout + (size_t)tp * BATCH,
            lp_parts + (size_t)tp * 512,
            eosP, t > 0 ? 1 : 0);
    }
    {   // final output step (t = STEPS-1)
        const f16* hi = (STEPS & 1) ? hTh_b : hTh_a;
        const f16* lo = (STEPS & 1) ? hTl_b : hTl_a;
        out_mfma<<<512, 64, 0, stream>>>(
            hi, lo, Wout_h, Wout_l, b_out, maskbuf,
            msg + (size_t)(STEPS - 1) * BATCH * VOCAB,
            maskout + (size_t)(STEPS - 1) * BATCH,
            lp_parts + (size_t)(STEPS - 1) * 512,
            eosP);
    }
    reduce_lp_kernel<<<1, 256, 0, stream>>>(lp_parts, STEPS * 512, lp_out);
}

// Round 11
// 2395.812 us; speedup vs baseline: 1.0650x; 1.0650x over previous
//
#include <hip/hip_runtime.h>
#include <math.h>

#define BATCH 16384
#define HDIM  512
#define VOCAB 32
#define STEPS 20
#define G4    2048

typedef _Float16 f16;
typedef _Float16 f16x8 __attribute__((ext_vector_type(8)));
typedef float    f32x16 __attribute__((ext_vector_type(16)));

#define SH   256.0f            // h pre-scale before fp16 split
#define SW   1024.0f           // W pre-scale before fp16 split
#define SINV (1.0f / (SH * SW))

// Fragment-ordered global images (granule = 16 B = 8 f16 = one lane's A/B frag):
//  hT  [kk:32][mb:512][lane:64]          granule(kk,mb,lane) =
//        h[m = mb*32 + (lane&31)][k = kk*16 + (lane>>5)*8 .. +8]
//  Wimg row r = jb*128 + kc*8 + ks*4 + g, granule(r,lane) =
//        W[n = g*512 + jb*32 + (lane&31)][k = kc*32 + ks*16 + (lane>>5)*8 .. +8]
//  Wout row r = kc*2 + ks (32 rows), granule(r,lane) =
//        W_out[v = lane&31][k = kc*32 + ks*16 + (lane>>5)*8 .. +8]

__device__ __forceinline__ void gload16(const void* g, void* l) {
#if defined(__has_builtin) && __has_builtin(__builtin_amdgcn_global_load_lds)
    __builtin_amdgcn_global_load_lds(
        (const __attribute__((address_space(1))) void*)g,
        (__attribute__((address_space(3))) void*)l, 16, 0, 0);
#else
    *(float4*)l = *(const float4*)g;
#endif
}

__device__ __forceinline__ float fsig(float x)  { return 1.0f / (1.0f + __expf(-x)); }
__device__ __forceinline__ float ftanh(float x) { return 1.0f - 2.0f / (__expf(2.0f * x) + 1.0f); }

// ---------------------------------------------------------------------------
// init / prep kernels (once per launch, outside the step loop)
// ---------------------------------------------------------------------------
__global__ void init_xb_kernel(const float* __restrict__ W_ih,
                               const float* __restrict__ b_ih,
                               const float* __restrict__ b_hh,
                               const float* __restrict__ x0,
                               float* __restrict__ xb) {
    int n = blockIdx.x * blockDim.x + threadIdx.x;
    if (n >= G4) return;
    float s = b_ih[n] + b_hh[n];
    const float* wr = W_ih + (size_t)n * VOCAB;
    #pragma unroll
    for (int v = 0; v < VOCAB; v++) s += wr[v] * x0[v];
    xb[n] = s;
}

__global__ void init_mask_kernel(float* __restrict__ mask) {
    int b = blockIdx.x * blockDim.x + threadIdx.x;
    if (b < BATCH) mask[b] = 1.0f;
}

// W_hh (fp32 [2048][512]) -> fragment-ordered split images (131072 granules)
__global__ void wimg_kernel(const float* __restrict__ W_hh,
                            f16* __restrict__ Wh, f16* __restrict__ Wl) {
    size_t g  = (size_t)blockIdx.x * 256 + threadIdx.x;   // granule id
    int ln = g & 63;  size_t r = g >> 6;                   // r = ((jb*16+kc)*2+ks)*4+gg
    int gg = r & 3;   size_t r2 = r >> 2;
    int ks = r2 & 1;  size_t r3 = r2 >> 1;
    int kc = r3 & 15; int jb = (int)(r3 >> 4);
    int n = gg * 512 + jb * 32 + (ln & 31);
    int k = kc * 32 + ks * 16 + (ln >> 5) * 8;
    const float* s = W_hh + (size_t)n * HDIM + k;
    f16x8 vh, vl;
    #pragma unroll
    for (int i = 0; i < 8; i++) {
        float x = s[i] * SW;
        f16 h = (f16)x;
        vh[i] = h;
        vl[i] = (f16)(x - (float)h);
    }
    *(f16x8*)(Wh + g * 8) = vh;
    *(f16x8*)(Wl + g * 8) = vl;
}

// W_out (fp32 [32][512]) -> fragment-ordered split images (2048 granules)
__global__ void woutimg_kernel(const float* __restrict__ W_out,
                               f16* __restrict__ Oh, f16* __restrict__ Ol) {
    int g  = blockIdx.x * 256 + threadIdx.x;   // 0..2047
    int ln = g & 63;
    int r  = g >> 6;                            // 0..31 = kc*2 + ks
    int kc = r >> 1, ks = r & 1;
    int v  = ln & 31;
    int k  = kc * 32 + ks * 16 + (ln >> 5) * 8;
    const float* s = W_out + (size_t)v * HDIM + k;
    f16x8 vh, vl;
    #pragma unroll
    for (int i = 0; i < 8; i++) {
        float x = s[i] * SW;
        f16 h = (f16)x;
        vh[i] = h;
        vl[i] = (f16)(x - (float)h);
    }
    *(f16x8*)(Oh + (size_t)g * 8) = vh;
    *(f16x8*)(Ol + (size_t)g * 8) = vl;
}

// enc_h (fp32 [16384][512]) -> fragment-ordered split hT images (1048576 granules)
__global__ void hT_init_kernel(const float* __restrict__ src,
                               f16* __restrict__ dh, f16* __restrict__ dl) {
    size_t g = (size_t)blockIdx.x * 256 + threadIdx.x;    // granule id
    int ln = g & 63;  size_t r = g >> 6;                   // r = kk*512 + mb
    int mb = (int)(r & 511); int kk = (int)(r >> 9);
    int m = mb * 32 + (ln & 31);
    int k = kk * 16 + (ln >> 5) * 8;
    const float* s = src + (size_t)m * HDIM + k;
    f16x8 vh, vl;
    #pragma unroll
    for (int i = 0; i < 8; i++) {
        float x = s[i] * SH;
        f16 h = (f16)x;
        vh[i] = h;
        vl[i] = (f16)(x - (float)h);
    }
    *(f16x8*)(dh + g * 8) = vh;
    *(f16x8*)(dl + g * 8) = vl;
}

// ---------------------------------------------------------------------------
// Output-step body: one wave computes logits/argmax/softmax for 32 batch rows.
// No LDS, no barriers.
// ---------------------------------------------------------------------------
__device__ __forceinline__ void out_body(int lane, int mb,
        const f16* __restrict__ hTh, const f16* __restrict__ hTl,
        const f16* __restrict__ Oh,  const f16* __restrict__ Ol,
        const float* __restrict__ b_out,
        float* __restrict__ mask, float* __restrict__ msg_t,
        float* __restrict__ maskout_t, float* __restrict__ lp_part, int eos) {
    const int half = lane >> 5;
    const int l31  = lane & 31;

    f32x16 acc;
    #pragma unroll
    for (int r = 0; r < 16; r++) acc[r] = 0.0f;

    f16x8 ah[3][2], al[3][2], bh[3][2], bl[3][2];
    auto load_frags = [&](int kc, int buf) {
        #pragma unroll
        for (int ks = 0; ks < 2; ks++) {
            size_t ga = ((size_t)(kc * 2 + ks) * 512 + mb) * 64 + lane;
            size_t gb = ((size_t)(kc * 2 + ks)) * 64 + lane;
            ah[buf][ks] = *(const f16x8*)(hTh + ga * 8);
            al[buf][ks] = *(const f16x8*)(hTl + ga * 8);
            bh[buf][ks] = *(const f16x8*)(Oh + gb * 8);
            bl[buf][ks] = *(const f16x8*)(Ol + gb * 8);
        }
    };

    load_frags(0, 0);
    load_frags(1, 1);
    for (int kc = 0; kc < 16; kc++) {
        if (kc < 14) load_frags(kc + 2, (kc + 2) % 3);
        int b = kc % 3;
        #pragma unroll
        for (int ks = 0; ks < 2; ks++) {
            acc = __builtin_amdgcn_mfma_f32_32x32x16_f16(ah[b][ks], bh[b][ks], acc, 0, 0, 0);
            acc = __builtin_amdgcn_mfma_f32_32x32x16_f16(ah[b][ks], bl[b][ks], acc, 0, 0, 0);
            acc = __builtin_amdgcn_mfma_f32_32x32x16_f16(al[b][ks], bh[b][ks], acc, 0, 0, 0);
        }
    }

    const float bo = b_out[l31];
    const int   m0 = mb * 32;
    float lpacc = 0.0f;

    #pragma unroll
    for (int reg = 0; reg < 16; reg++) {
        int row = (reg & 3) + 8 * (reg >> 2) + 4 * half;
        int m   = m0 + row;
        float logit = acc[reg] * SINV + bo;

        float mval = logit;
        int   midx = l31;
        #pragma unroll
        for (int off = 16; off > 0; off >>= 1) {
            float ov = __shfl_xor(mval, off, 32);
            int   oi = __shfl_xor(midx, off, 32);
            if (ov > mval || (ov == mval && oi < midx)) { mval = ov; midx = oi; }
        }
        float s = __expf(logit - mval);
        #pragma unroll
        for (int off = 16; off > 0; off >>= 1) s += __shfl_xor(s, off, 32);

        msg_t[(size_t)m * VOCAB + l31] = (l31 == midx) ? 1.0f : 0.0f;
        if (l31 == 0) {
            float mo = mask[m];
            maskout_t[m] = mo;
            lpacc += mo * (-__logf(s));
            if (midx == eos) mask[m] = 0.0f;
        }
    }
    lpacc += __shfl_xor(lpacc, 32);   // fold lane 32's partial into lane 0
    if (lane == 0) lp_part[mb] = lpacc;
}

// ---------------------------------------------------------------------------
// Fused step kernel.  Blocks 0..127 (4 waves each): output step for h(t-1),
// placed FIRST so gemm blocks backfill behind them.  Blocks 128..2175: MFMA
// GEMM (3-pass fp16 split) + LSTM cell -> h(t) images.
// Block tile 128m x 128n; wave tile 32m x 128n (acc = 64 AGPR); 64 arch VGPR
// + 64 acc = 128 regs.  LDS exactly 32768 B (Blds 32 KB; hstage 16.9 KB
// overlays it) -> up to 5 LDS block-slots/CU.
// Swizzle jb = gb&15 fastest (R9-measured best; mt-pinned variant regressed).
// mfma_f32_32x32x16_f16: D[row=(reg&3)+8*(reg>>2)+4*(lane>>5)][col=lane&31].
// ---------------------------------------------------------------------------
__global__ __launch_bounds__(256, 4)
void step_fused(const f16* __restrict__ hT_h, const f16* __restrict__ hT_l,
                f16* __restrict__ hTo_h, f16* __restrict__ hTo_l,
                const float* __restrict__ c_in,
                float* __restrict__ c_out,
                const f16* __restrict__ Wimg_h, const f16* __restrict__ Wimg_l,
                const float* __restrict__ xb,
                const f16* __restrict__ Oh, const f16* __restrict__ Ol,
                const float* __restrict__ b_out,
                float* __restrict__ mask,
                float* __restrict__ msg_p,      // step t-1 outputs
                float* __restrict__ maskout_p,
                float* __restrict__ lp_p,
                const int* __restrict__ eos_ptr,
                int has_out) {
    __shared__ __align__(16) char smem_raw[32768];   // B dbuf 32 KB | hstage 16.9 KB
    f16* Blds = (f16*)smem_raw;   // row = (buf*16 + sp*8 + ks*4 + g), 512 f16/row

    const int tid  = threadIdx.x;
    const int lane = tid & 63;
    const int wave = tid >> 6;
    const int bid  = blockIdx.x;

    if (bid < 128) {                // ---- output-step role (for h(t-1)) ----
        if (!has_out) return;
        int mb = bid * 4 + wave;                   // 0..511
        out_body(lane, mb, hT_h, hT_l, Oh, Ol, b_out,
                 mask, msg_p, maskout_p, lp_p, *eos_ptr);
        return;
    }

    // ---- GEMM role ----
    const int gb   = bid - 128;       // 0..2047
    const int jb   = gb & 15;         // n-slice (fastest; R9-measured best)
    const int mt   = gb >> 4;         // 0..127, 128-m tile
    const int spw  = wave >> 1;       // staging: split image
    const int ksw  = wave & 1;        // staging: k-sub
    const int mbA  = mt * 4 + wave;   // this wave's 32-m granule row
    const int m0   = mt * 128;
    const int j0   = jb * 32;
    const int half = lane >> 5;
    const int l31  = lane & 31;

    f32x16 acc[4];                    // [gate] for this wave's 32m x 32j
    #pragma unroll
    for (int g = 0; g < 4; g++)
        #pragma unroll
        for (int r = 0; r < 16; r++) acc[g][r] = 0.0f;

    const f16* bsrc0 = (spw ? Wimg_l : Wimg_h)
                     + ((size_t)jb * 128 + ksw * 4) * 512 + lane * 8;
    f16* bdst0 = Blds + (size_t)(spw * 8 + ksw * 4) * 512 + lane * 8;

    auto stage_b = [&](int kc, int buf) {
        const f16* s = bsrc0 + (size_t)kc * 4096;
        f16* d = bdst0 + buf * 16 * 512;
        #pragma unroll
        for (int g = 0; g < 4; g++)
            gload16(s + g * 512, d + g * 512);
    };

    const size_t abase0 = (size_t)mbA * 512 + lane * 8;
    auto load_ah = [&](int kc, f16x8 (&dst)[2]) {
        #pragma unroll
        for (int ks = 0; ks < 2; ks++)
            dst[ks] = *(const f16x8*)(hT_h + abase0
                           + (size_t)(kc * 2 + ks) * (512 * 512));
    };
    auto load_al = [&](int kc, f16x8 (&dst)[2]) {
        #pragma unroll
        for (int ks = 0; ks < 2; ks++)
            dst[ks] = *(const f16x8*)(hT_l + abase0
                           + (size_t)(kc * 2 + ks) * (512 * 512));
    };

    // pass-major order; per-accumulator accumulation order (hh, hl, lh) is
    // unchanged from prior rounds -> bit-identical results.
    auto compute = [&](f16x8 (&ah)[2], f16x8 (&al)[2], int buf) {
        #pragma unroll
        for (int ks = 0; ks < 2; ks++) {
            f16x8 bh[4], bl[4];
            #pragma unroll
            for (int g = 0; g < 4; g++) {
                bh[g] = *(const f16x8*)(Blds + (size_t)(buf * 16 + ks * 4 + g) * 512 + lane * 8);
                bl[g] = *(const f16x8*)(Blds + (size_t)(buf * 16 + 8 + ks * 4 + g) * 512 + lane * 8);
            }
            #pragma unroll
            for (int g = 0; g < 4; g++)
                acc[g] = __builtin_amdgcn_mfma_f32_32x32x16_f16(ah[ks], bh[g], acc[g], 0, 0, 0);
            #pragma unroll
            for (int g = 0; g < 4; g++)
                acc[g] = __builtin_amdgcn_mfma_f32_32x32x16_f16(ah[ks], bl[g], acc[g], 0, 0, 0);
            #pragma unroll
            for (int g = 0; g < 4; g++)
                acc[g] = __builtin_amdgcn_mfma_f32_32x32x16_f16(al[ks], bh[g], acc[g], 0, 0, 0);
        }
    };

    f16x8 ah0[2], ah1[2], al0[2], al1[2];
    stage_b(0, 0);
    load_ah(0, ah0);
    load_al(0, al0);
    for (int kc2 = 0; kc2 < 8; kc2++) {
        const int kc = kc2 * 2;
        __syncthreads();                 // buf0(kc) + ah0/al0 ready (issued 1 chunk ago)
        stage_b(kc + 1, 1);
        load_ah(kc + 1, ah1);
        load_al(kc + 1, al1);
        compute(ah0, al0, 0);
        __syncthreads();                 // buf1(kc+1) + ah1/al1 ready
        stage_b(kc + 2, 0);              // kc+2==16 on last iter: benign overrun
        load_ah(kc + 2, ah0);            //   (reads stay inside workspace)
        load_al(kc + 2, al0);
        compute(ah1, al1, 1);
    }

    // ---- epilogue: cell update + hT-image production via LDS bounce ----
    __syncthreads();
    unsigned int* hstage = (unsigned int*)smem_raw;   // [m:128][j:33] packed (hi,lo)

    const float xbi = xb[0 * HDIM + j0 + l31];
    const float xbf = xb[1 * HDIM + j0 + l31];
    const float xbg = xb[2 * HDIM + j0 + l31];
    const float xbo = xb[3 * HDIM + j0 + l31];
    #pragma unroll
    for (int reg = 0; reg < 16; reg++) {
        int row = (reg & 3) + 8 * (reg >> 2) + 4 * half;
        int ml  = wave * 32 + row;                 // local m (0..127)
        float gi = acc[0][reg] * SINV + xbi;
        float gf = acc[1][reg] * SINV + xbf;
        float gg = acc[2][reg] * SINV + xbg;
        float go = acc[3][reg] * SINV + xbo;
        float si = fsig(gi);
        float sf = fsig(gf);
        float tg = ftanh(gg);
        float so = fsig(go);
        size_t idx = (size_t)(m0 + ml) * HDIM + j0 + l31;
        float cn = sf * c_in[idx] + si * tg;
        c_out[idx] = cn;
        float hs = so * ftanh(cn) * SH;
        f16 hh = (f16)hs;
        f16 hl = (f16)(hs - (float)hh);
        union { f16 h[2]; unsigned int u; } pk;
        pk.h[0] = hh; pk.h[1] = hl;
        hstage[ml * 33 + l31] = pk.u;
    }
    __syncthreads();

    // emit 512 granules: q = (ksp<<8)|(mbl<<6)|ln
    #pragma unroll
    for (int s = 0; s < 2; s++) {
        int q   = tid + s * 256;
        int ksp = q >> 8;
        int mbl = (q >> 6) & 3;
        int ln  = q & 63;
        int mrow = mbl * 32 + (ln & 31);           // local m (0..127)
        int jj8  = ksp * 16 + (ln >> 5) * 8;
        f16x8 vh, vl;
        #pragma unroll
        for (int i = 0; i < 8; i++) {
            union { unsigned int u; f16 h[2]; } pk;
            pk.u = hstage[mrow * 33 + jj8 + i];
            vh[i] = pk.h[0];
            vl[i] = pk.h[1];
        }
        size_t gq = ((size_t)(jb * 2 + ksp) * 512 + mt * 4 + mbl) * 64 + ln;
        *(f16x8*)(hTo_h + gq * 8) = vh;
        *(f16x8*)(hTo_l + gq * 8) = vl;
    }
}

// standalone output step (final step only)
__global__ __launch_bounds__(64)
void out_mfma(const f16* __restrict__ hTh, const f16* __restrict__ hTl,
              const f16* __restrict__ Oh, const f16* __restrict__ Ol,
              const float* __restrict__ b_out,
              float* __restrict__ mask,
              float* __restrict__ msg_t,
              float* __restrict__ maskout_t,
              float* __restrict__ lp_part,
              const int* __restrict__ eos_ptr) {
    out_body(threadIdx.x, blockIdx.x, hTh, hTl, Oh, Ol, b_out,
             mask, msg_t, maskout_t, lp_part, *eos_ptr);
}

__global__ void reduce_lp_kernel(const float* __restrict__ parts, int n,
                                 float* __restrict__ out) {
    __shared__ float sm[256];
    float s = 0.0f;
    for (int i = threadIdx.x; i < n; i += 256) s += parts[i];
    sm[threadIdx.x] = s;
    __syncthreads();
    for (int off = 128; off > 0; off >>= 1) {
        if (threadIdx.x < off) sm[threadIdx.x] += sm[threadIdx.x + off];
        __syncthreads();
    }
    if (threadIdx.x == 0) *out = sm[0];
}

// ---------------------------------------------------------------------------
extern "C" void kernel_launch(void* const* d_in, const int* in_sizes, int n_in,
                              void* d_out, int out_size, void* d_ws, size_t ws_size,
                              hipStream_t stream) {
    const float* enc_h  = (const float*)d_in[0];
    const float* enc_c  = (const float*)d_in[1];
    const float* W_ih   = (const float*)d_in[2];
    const float* b_ih   = (const float*)d_in[3];
    const float* W_hh   = (const float*)d_in[4];
    const float* b_hh   = (const float*)d_in[5];
    const float* W_out  = (const float*)d_in[6];
    const float* b_out  = (const float*)d_in[7];
    const float* x0     = (const float*)d_in[8];
    const int*   eosP   = (const int*)d_in[9];

    float* out     = (float*)d_out;
    float* msg     = out;                                   // [20,16384,32]
    float* maskout = out + (size_t)STEPS * BATCH * VOCAB;   // [20,1,16384]
    float* lp_out  = maskout + (size_t)STEPS * BATCH;       // scalar

    const size_t NH = (size_t)BATCH * HDIM;                 // 8388608
    char* w = (char*)d_ws;
    f16* hTh_a = (f16*)w;            w += NH * sizeof(f16);
    f16* hTl_a = (f16*)w;            w += NH * sizeof(f16);
    f16* hTh_b = (f16*)w;            w += NH * sizeof(f16);
    f16* hTl_b = (f16*)w;            w += NH * sizeof(f16);
    float* cbuf = (float*)w;         w += NH * sizeof(float);
    f16* Wimg_h = (f16*)w;           w += (size_t)G4 * HDIM * sizeof(f16);
    f16* Wimg_l = (f16*)w;           w += (size_t)G4 * HDIM * sizeof(f16);
    f16* Wout_h = (f16*)w;           w += (size_t)VOCAB * HDIM * sizeof(f16);
    f16* Wout_l = (f16*)w;           w += (size_t)VOCAB * HDIM * sizeof(f16);
    float* xb = (float*)w;           w += G4 * sizeof(float);
    float* maskbuf = (float*)w;      w += BATCH * sizeof(float);
    float* lp_parts = (float*)w;     // STEPS * 512 floats

    init_mask_kernel<<<(BATCH + 255) / 256, 256, 0, stream>>>(maskbuf);
    init_xb_kernel<<<(G4 + 255) / 256, 256, 0, stream>>>(W_ih, b_ih, b_hh, x0, xb);
    wimg_kernel<<<(G4 * HDIM / 8) / 256, 256, 0, stream>>>(W_hh, Wimg_h, Wimg_l);
    woutimg_kernel<<<8, 256, 0, stream>>>(W_out, Wout_h, Wout_l);
    hT_init_kernel<<<(int)((NH / 8) / 256), 256, 0, stream>>>(enc_h, hTh_a, hTl_a);

    for (int t = 0; t < STEPS; t++) {
        const f16* hi_in = (t & 1) ? hTh_b : hTh_a;
        const f16* lo_in = (t & 1) ? hTl_b : hTl_a;
        f16* hi_out      = (t & 1) ? hTh_a : hTh_b;
        f16* lo_out      = (t & 1) ? hTl_a : hTl_b;
        const float* cin = (t == 0) ? enc_c : cbuf;   // step 0 reads enc_c directly
        int tp = (t > 0) ? (t - 1) : 0;   // previous step (outputs written iff t>0)
        step_fused<<<2176, 256, 0, stream>>>(
            hi_in, lo_in, hi_out, lo_out, cin, cbuf, Wimg_h, Wimg_l, xb,
            Wout_h, Wout_l, b_out, maskbuf,
            msg + (size_t)tp * BATCH * VOCAB,
            maskout + (size_t)tp * BATCH,
            lp_parts + (size_t)tp * 512,
            eosP, t > 0 ? 1 : 0);
    }
    {   // final output step (t = STEPS-1)
        const f16* hi = (STEPS & 1) ? hTh_b : hTh_a;
        const f16* lo = (STEPS & 1) ? hTl_b : hTl_a;
        out_mfma<<<512, 64, 0, stream>>>(
            hi, lo, Wout_h, Wout_l, b_out, maskbuf,
            msg + (size_t)(STEPS - 1) * BATCH * VOCAB,
            maskout + (size_t)(STEPS - 1) * BATCH,
            lp_parts + (size_t)(STEPS - 1) * 512,
            eosP);
    }
    reduce_lp_kernel<<<1, 256, 0, stream>>>(lp_parts, STEPS * 512, lp_out);
}